// Round 1
// baseline (334.074 us; speedup 1.0000x reference)
//
#include <hip/hip_runtime.h>
#include <math.h>

// Output row (70 floats): [coords(3) | enc(64) | colours(3)]
// enc[2j] = sin(i * 10^(-j/8)), enc[2j+1] = cos(...), j = 0..31
//
// v2 design: pure streaming, no LDS tile, no per-tile barriers.
// Each thread owns one 16B-aligned float4 of the output (grid-stride).
// For each element: (row, c) from one magic-div per float4 + increments;
//   c <  3  -> coords  = pc[row*6 + c]        (masked gather, L2-resident)
//   c >= 67 -> colours = pc[row*6 + c - 64]
//   else    -> enc: double-precision range reduction (bit-identical to the
//              previous passing kernel: t = row*w2[j]; frac = t - rint(t);
//              rad = float(frac*2pi); __sinf/__cosf) -> absmax unchanged.
// Stores issue continuously from all waves (fill-kernel-like behavior),
// instead of bursting after a compute phase + __syncthreads.
//
// Only LDS use: the 32-entry w2[] double table (256 B), built once per block
// with the exact same expression as before (bit-identical values).

#define BLOCK 256

__global__ __launch_bounds__(256) void pe_kernel(const float* __restrict__ pc,
                                                 float* __restrict__ out,
                                                 int n_rows) {
    __shared__ double s_w2[32];          // 10^(-j/8) / (2*pi)
    const int tid = threadIdx.x;
    if (tid < 32) {
        // inv_two_pi * 10000^(-tid/32); log() folds at compile time
        s_w2[tid] = 0.15915494309189533577 * exp(-(double)tid * (log(10000.0) / 32.0));
    }
    __syncthreads();                     // once per block, not per tile

    const double two_pi = 6.2831853071795864769;
    const unsigned int total = (unsigned int)n_rows * 70u;   // 7e7 < 2^31
    const unsigned int nvec  = total >> 2;                   // aligned float4s
    const unsigned int stride = gridDim.x * blockDim.x;

    float4* __restrict__ out4 = reinterpret_cast<float4*>(out);

    for (unsigned int i = blockIdx.x * blockDim.x + tid; i < nvec; i += stride) {
        const unsigned int g0 = i * 4u;
        unsigned int row = g0 / 70u;             // magic-mul (constant div)
        unsigned int c   = g0 - row * 70u;
        float4 v;
        float* ve = &v.x;
#pragma unroll
        for (int m = 0; m < 4; ++m) {
            float val;
            if (c < 3u) {                        // coords (few lanes, masked)
                val = pc[row * 6u + c];
            } else if (c >= 67u) {               // colours (few lanes, masked)
                val = pc[row * 6u + (c - 64u)];
            } else {                             // enc (majority of lanes)
                const unsigned int jj = c - 3u;
                const unsigned int j  = jj >> 1;
                const double t    = (double)row * s_w2[j];   // revolutions
                const double frac = t - rint(t);             // [-0.5, 0.5]
                const float  rad  = (float)(frac * two_pi);  // [-pi, pi]
                val = (jj & 1u) ? __cosf(rad) : __sinf(rad); // native trans
            }
            ve[m] = val;
            // advance (row, c) without another division
            ++c;
            if (c == 70u) { c = 0u; ++row; }
        }
        out4[i] = v;                             // aligned, fully coalesced
    }

    // ragged tail (total % 4 != 0 only when n_rows is odd)
    const unsigned int rem = total & 3u;
    if (rem && blockIdx.x == 0 && (unsigned int)tid < rem) {
        const unsigned int g = (nvec << 2) + (unsigned int)tid;
        const unsigned int row = g / 70u;
        const unsigned int c   = g - row * 70u;
        float val;
        if (c < 3u) {
            val = pc[row * 6u + c];
        } else if (c >= 67u) {
            val = pc[row * 6u + (c - 64u)];
        } else {
            const unsigned int jj = c - 3u;
            const unsigned int j  = jj >> 1;
            const double t    = (double)row * s_w2[j];
            const double frac = t - rint(t);
            const float  rad  = (float)(frac * two_pi);
            val = (jj & 1u) ? __cosf(rad) : __sinf(rad);
        }
        out[g] = val;
    }
}

extern "C" void kernel_launch(void* const* d_in, const int* in_sizes, int n_in,
                              void* d_out, int out_size, void* d_ws, size_t ws_size,
                              hipStream_t stream) {
    const float* pc = (const float*)d_in[0];
    float* out = (float*)d_out;
    const int n_rows = in_sizes[0] / 6;
    const unsigned int nvec = ((unsigned int)n_rows * 70u) >> 2;
    // memory-bound: ~8 blocks/CU x 256 CUs, grid-stride the rest (G11)
    unsigned int grid = (nvec + BLOCK - 1) / BLOCK;
    if (grid > 2048u) grid = 2048u;
    if (grid == 0u) grid = 1u;
    pe_kernel<<<dim3(grid), dim3(BLOCK), 0, stream>>>(pc, out, n_rows);
}

// Round 2
// 297.190 us; speedup vs baseline: 1.1241x; 1.1241x over previous
//
#include <hip/hip_runtime.h>
#include <math.h>

// Output row (70 floats): [coords(3) | enc(64) | colours(3)]
// enc[2j] = sin(i * 10^(-j/8)), enc[2j+1] = cos(...), j = 0..31
//
// v3: back to the LDS-staged design (v1, the faster structure), with the
// per-block overheads removed:
//  - 64 rows/block (15625 blocks for n=1e6, exact -> no ragged fast path)
//  - no exp() table init, no table barrier: w2(j) = inv2pi * 10^(-j/8)
//    built from 5 conditional f64 multiplies on literal constants
//  - sin/cos fed in REVOLUTIONS directly (v_sin_f32 semantics) -- skips
//    the x2pi then x1/(2pi) round trip of __sinf
//  - input float4 loads issued BEFORE the sincos phase (latency hides
//    under ~8 f64+trans iterations)
// LDS 64*70*4 = 17920 B -> 8 blocks/CU (143 KB), pinned via launch_bounds.

#define ROWS_PER_BLOCK 64
#define OUTC 70
#define FLOATS_PER_BLOCK (ROWS_PER_BLOCK * OUTC)     // 4480
#define VEC4_PER_BLOCK   (FLOATS_PER_BLOCK / 4)      // 1120
#define IN_FLOATS_PER_BLOCK (ROWS_PER_BLOCK * 6)     // 384
#define IN_VEC4_PER_BLOCK   (IN_FLOATS_PER_BLOCK/4)  // 96

__global__ __launch_bounds__(256, 8) void pe_kernel(const float* __restrict__ pc,
                                                    float* __restrict__ out,
                                                    int n_rows) {
    __shared__ float s_tile[FLOATS_PER_BLOCK];

    const int tid = threadIdx.x;
    const int b = blockIdx.x;
    const int rowBase = b * ROWS_PER_BLOCK;

    // ---- per-thread w2 = inv_two_pi * 10^(-j/8), j = tid & 31 ----
    // (5 f64 muls on literals; replaces the per-block exp() + LDS table)
    const int j = tid & 31;
    double w = 0.15915494309189533577;               // 1/(2*pi)
    if (j & 1)  w *= 0.74989420933245585;            // 10^(-1/8)
    if (j & 2)  w *= 0.5623413251903491;             // 10^(-1/4)
    if (j & 4)  w *= 0.31622776601683794;            // 10^(-1/2)
    if (j & 8)  w *= 0.1;                            // 10^(-1)
    if (j & 16) w *= 0.01;                           // 10^(-2)

    // ---- issue input loads early (latency hides under Phase A1) ----
    const long long in_total = (long long)n_rows * 6;
    float4 vin;
    bool fast_in = false;
    long long f0 = 0;
    if (tid < IN_VEC4_PER_BLOCK) {
        const long long inBase = (long long)b * IN_FLOATS_PER_BLOCK;
        f0 = inBase + tid * 4;
        if (f0 + 3 < in_total) {
            vin = reinterpret_cast<const float4*>(pc)[inBase / 4 + tid];
            fast_in = true;
        }
    }

    // ---- Phase A1: enc pairs into LDS (uniform, no divergence) ----
    // 256 threads x 8 pairs = 2048 pairs = 64 rows x 32 j's
    int r = tid >> 5;                    // local row 0..7, step 8
#pragma unroll 4
    for (int k = 0; k < 8; ++k) {
        const double t = (double)(rowBase + r) * w;    // revolutions
        const double frac = t - rint(t);               // [-0.5, 0.5]
        const float fr = (float)frac;
        const int pos = r * OUTC + 3 + 2 * j;
        s_tile[pos]     = __builtin_amdgcn_sinf(fr);   // sin(2*pi*fr)
        s_tile[pos + 1] = __builtin_amdgcn_cosf(fr);   // cos(2*pi*fr)
        r += 8;
    }

    // ---- Phase A2: scatter coords/colours from the prefetched float4 ----
    if (tid < IN_VEC4_PER_BLOCK) {
        if (fast_in) {
            const float* ve = &vin.x;
#pragma unroll
            for (int m = 0; m < 4; ++m) {
                const int fl = tid * 4 + m;            // local input idx 0..383
                const int row = fl / 6;                // magic-mul
                const int c = fl - row * 6;
                const int col = (c < 3) ? c : (c + 64); // 67..69 for colours
                s_tile[row * OUTC + col] = ve[m];
            }
        } else {                                       // ragged tail block
            for (int m = 0; m < 4; ++m) {
                const long long f = f0 + m;
                if (f < in_total) {
                    const float val = pc[f];
                    const int fl = tid * 4 + m;
                    const int row = fl / 6;
                    const int c = fl - row * 6;
                    const int col = (c < 3) ? c : (c + 64);
                    s_tile[row * OUTC + col] = val;
                }
            }
        }
    }
    __syncthreads();

    // ---- Phase B: LDS tile -> global, 16B-aligned float4 stores ----
    const long long outBase = (long long)b * FLOATS_PER_BLOCK;  // mult of 4
    const long long total = (long long)n_rows * OUTC;
    float4* __restrict__ out4 = reinterpret_cast<float4*>(out);
    if (outBase + FLOATS_PER_BLOCK <= total) {
        // full block (always true for n = 1e6): unguarded stream
        for (int i = tid; i < VEC4_PER_BLOCK; i += 256) {
            float4 v;
            v.x = s_tile[i * 4 + 0];
            v.y = s_tile[i * 4 + 1];
            v.z = s_tile[i * 4 + 2];
            v.w = s_tile[i * 4 + 3];
            out4[outBase / 4 + i] = v;
        }
    } else {
        for (int i = tid; i < VEC4_PER_BLOCK; i += 256) {
            const long long g = outBase + (long long)i * 4;
            if (g + 4 <= total) {
                float4 v;
                v.x = s_tile[i * 4 + 0];
                v.y = s_tile[i * 4 + 1];
                v.z = s_tile[i * 4 + 2];
                v.w = s_tile[i * 4 + 3];
                out4[outBase / 4 + i] = v;
            } else {
                for (int m = 0; m < 4; ++m)
                    if (g + m < total) out[g + m] = s_tile[i * 4 + m];
            }
        }
    }
}

extern "C" void kernel_launch(void* const* d_in, const int* in_sizes, int n_in,
                              void* d_out, int out_size, void* d_ws, size_t ws_size,
                              hipStream_t stream) {
    const float* pc = (const float*)d_in[0];
    float* out = (float*)d_out;
    const int n_rows = in_sizes[0] / 6;
    const int grid = (n_rows + ROWS_PER_BLOCK - 1) / ROWS_PER_BLOCK;  // 15625
    pe_kernel<<<dim3(grid), dim3(256), 0, stream>>>(pc, out, n_rows);
}